// Round 16
// baseline (86.900 us; speedup 1.0000x reference)
//
#include <hip/hip_runtime.h>

#define N 64
#define MARGIN 0.1f
#define WAVES_PER_BLOCK 4
#define NBLOCKS 1024   // 4096 waves, 8 rows/wave; fewer same-address atomics

// closed form (verified R2..R15, absmax 0.0):
//   p_e = #{k: lab_k < lab_e},  u_e = sc_e - MARGIN*p_e
//   row_loss = sum_e u_e*(31.5 - p_e) + 0.25*sum_{e,k}|u_e - u_k|
//
// R16: delete the serial tail. R11..R15 plateau at ~84us; the trailing
// 1-block mmrl_reduce kernel is a pure serial tail (launch + full-grid drain
// + 1-CU execution ~4-6us). Replace with a 4-byte memset BEFORE the main
// kernel (cheap leading dispatch) + per-block atomicAdd (1024 atomics,
// staggered by block completion -- only the drain tail serializes).
// Main-kernel body unchanged from R15 (sign-bit pass1 on SMEM float4,
// |u-u_k| pass2 on LDS float4, vcc-free chains).
__global__ __launch_bounds__(256) void mmrl_kernel(const float* __restrict__ scores,
                                                   const float* __restrict__ labels,
                                                   float* __restrict__ out,
                                                   int rows) {
    __shared__ float ubuf[WAVES_PER_BLOCK][N];
    __shared__ float wsum[WAVES_PER_BLOCK];

    const int lane = threadIdx.x & 63;
    const int w    = threadIdx.x >> 6;
    const int gwave = blockIdx.x * WAVES_PER_BLOCK + w;
    const int nwaves = NBLOCKS * WAVES_PER_BLOCK;

    float acc = 0.0f;

    for (int row = gwave; row < rows; row += nwaves) {
        const int base = __builtin_amdgcn_readfirstlane(row) * N;
        const float labv = labels[base + lane];   // coalesced per-lane copy
        const float scv  = scores[base + lane];

        // ---- pass 1: label rank p (SMEM float4 broadcasts; sign-bit counts) ----
        const float4* L4 = (const float4*)(labels + base);
        int p0 = 0, p1 = 0, p2 = 0, p3 = 0;       // accumulate 0 / -1
        #pragma unroll
        for (int kk = 0; kk < N / 4; ++kk) {
            const float4 a = L4[kk];
            p0 += __float_as_int(a.x - labv) >> 31;
            p1 += __float_as_int(a.y - labv) >> 31;
            p2 += __float_as_int(a.z - labv) >> 31;
            p3 += __float_as_int(a.w - labv) >> 31;
        }
        const int pv = -((p0 + p1) + (p2 + p3));

        const float u = fmaf(-MARGIN, (float)pv, scv);

        // ---- pass 2: sum_k |u - u_k| (LDS uniform float4 broadcasts) ----
        ubuf[w][lane] = u;
        const float4* U4 = (const float4*)ubuf[w];
        float A0 = 0.0f, A1 = 0.0f, A2 = 0.0f, A3 = 0.0f;
        #pragma unroll
        for (int kk = 0; kk < N / 4; ++kk) {
            const float4 a = U4[kk];
            A0 += fabsf(a.x - u);                  // v_sub + v_add with |..| mod
            A1 += fabsf(a.y - u);
            A2 += fabsf(a.z - u);
            A3 += fabsf(a.w - u);
        }
        const float rowabs = (A0 + A1) + (A2 + A3);

        // c = u*( (N-1)/2 - p ) + rowabs/4
        acc = fmaf(u, 31.5f - (float)pv, fmaf(0.25f, rowabs, acc));
    }

    // ---- wave reduction ----
    #pragma unroll
    for (int off = 32; off > 0; off >>= 1)
        acc += __shfl_down(acc, off, 64);

    if (lane == 0) wsum[w] = acc;
    __syncthreads();
    if (threadIdx.x == 0) {
        float s = 0.0f;
        #pragma unroll
        for (int i = 0; i < WAVES_PER_BLOCK; ++i) s += wsum[i];
        atomicAdd(out, s * (1.0f / (float)rows));   // plain device atomic, no fence
    }
}

extern "C" void kernel_launch(void* const* d_in, const int* in_sizes, int n_in,
                              void* d_out, int out_size, void* d_ws, size_t ws_size,
                              hipStream_t stream) {
    const float* scores = (const float*)d_in[0];
    const float* labels = (const float*)d_in[1];
    float* out = (float*)d_out;
    const int rows = in_sizes[0] / N;     // 32768

    (void)hipMemsetAsync(out, 0, sizeof(float), stream);  // leading 4B dispatch
    mmrl_kernel<<<NBLOCKS, 256, 0, stream>>>(scores, labels, out, rows);
}